// Round 3
// baseline (7302.885 us; speedup 1.0000x reference)
//
#include <hip/hip_runtime.h>
#include <hip/hip_bf16.h>

#define GB 2  // batch elems per convB / fused block

__device__ __forceinline__ float elu1(float v) { return v > 0.f ? v : expm1f(v); }

// ---------------- cnorm: ||cb_k||^2 per code ----------------
__global__ void cnorm_kernel(const float* __restrict__ cb, float* __restrict__ cnorm) {
    int g = blockIdx.x * blockDim.x + threadIdx.x;  // 0..8191  (q*1024+k)
    if (g >= 8 * 1024) return;
    const float* p = cb + (size_t)g * 256;
    float s = 0.f;
    for (int d = 0; d < 256; d += 4) {
        float4 v = *reinterpret_cast<const float4*>(p + d);
        s += v.x * v.x + v.y * v.y + v.z * v.z + v.w * v.w;
    }
    cnorm[g] = s;
}

// ---------------- weight transpose to lane-major layouts ----------------
__global__ void wtrans_kernel(const float* __restrict__ W1, const float* __restrict__ W2,
                              const float* __restrict__ W3, float* __restrict__ W1T,
                              float* __restrict__ W2T, float* __restrict__ W3T) {
    int g = blockIdx.x * blockDim.x + threadIdx.x;
    if (g < 8192) {  // W1
        int ci = g >> 7, c = g & 127;
        const float* src = W1 + c * 512 + ci * 8;
        float4 a = *reinterpret_cast<const float4*>(src);
        float4 b = *reinterpret_cast<const float4*>(src + 4);
        *reinterpret_cast<float4*>(W1T + g * 8) = a;
        *reinterpret_cast<float4*>(W1T + g * 8 + 4) = b;
    }
    int g2 = g - 8192;
    if (g2 >= 0 && g2 < 32768) {  // W2
        int ci = g2 >> 8, c = g2 & 255;
        const float* src = W2 + c * 1280 + ci * 10;
        float* dst = W2T + g2 * 10;
#pragma unroll
        for (int j = 0; j < 5; ++j)
            *reinterpret_cast<float2*>(dst + 2 * j) =
                *reinterpret_cast<const float2*>(src + 2 * j);
    }
    int g3 = g - 40960;
    if (g3 >= 0 && g3 < 65536) {  // W3 (only taps 6..11 are ever used)
        int ci = g3 >> 8, c = g3 & 255;
        const float* src = W3 + c * 3072 + ci * 12 + 6;
        float* dst = W3T + g3 * 6;
#pragma unroll
        for (int j = 0; j < 3; ++j)
            *reinterpret_cast<float2*>(dst + 2 * j) =
                *reinterpret_cast<const float2*>(src + 2 * j);
    }
}

// ================= SPLIT PATH =================
// convA: conv0 + conv1, one batch elem per block. LDS 32.7KB -> 4 blocks/CU.
__global__ __launch_bounds__(256, 4)
void convA_kernel(const float* __restrict__ audio,
                  const float* __restrict__ W0, const float* __restrict__ b0,
                  const float* __restrict__ W1T, const float* __restrict__ b1,
                  float* __restrict__ y1g) {
    __shared__ __align__(16) float xs[244];
    __shared__ __align__(16) float y0s[64 * 124];  // 4 left pad cols

    const int tid = threadIdx.x;
    const int b = blockIdx.x;

    if (tid < 64) {
        y0s[tid * 124 + 0] = 0.f; y0s[tid * 124 + 1] = 0.f;
        y0s[tid * 124 + 2] = 0.f; y0s[tid * 124 + 3] = 0.f;
    }
    if (tid < 242) xs[tid] = (tid < 2) ? 0.f : audio[b * 240 + tid - 2];
    __syncthreads();
    // ---- conv0 (1->64, k=4, s=2) + ELU ----
    {
        const int ci = tid >> 2, tg = tid & 3;
        float4 w = *reinterpret_cast<const float4*>(W0 + ci * 4);
        float bias = b0[ci];
        for (int t = tg; t < 120; t += 4) {
            float v = bias + w.x * xs[2 * t] + w.y * xs[2 * t + 1]
                           + w.z * xs[2 * t + 2] + w.w * xs[2 * t + 3];
            y0s[ci * 124 + 4 + t] = elu1(v);
        }
    }
    __syncthreads();
    // ---- conv1 (64->128, k=8, s=4) + ELU, ping-pong weight prefetch ----
    {
        const int c = tid >> 1, half = tid & 1, t0 = 15 * half;
        float acc[15];
        float bias = b1[c];
#pragma unroll
        for (int u = 0; u < 15; ++u) acc[u] = bias;
        const float* wbase = W1T + c * 8;  // + ci*1024

        auto body = [&](float4 wA, float4 wB, int ci) {
            const float* yb = y0s + ci * 124 + 4 * t0;
#pragma unroll
            for (int u = 0; u < 15; ++u) {
                float4 a = *reinterpret_cast<const float4*>(yb + 4 * u);
                float4 d = *reinterpret_cast<const float4*>(yb + 4 * u + 4);
                acc[u] += wA.x * a.x + wA.y * a.y + wA.z * a.z + wA.w * a.w
                        + wB.x * d.x + wB.y * d.y + wB.z * d.z + wB.w * d.w;
            }
        };

        float4 wA0 = *reinterpret_cast<const float4*>(wbase);
        float4 wB0 = *reinterpret_cast<const float4*>(wbase + 4);
        for (int ci = 0; ci < 64; ci += 2) {
            float4 wA1 = *reinterpret_cast<const float4*>(wbase + (ci + 1) * 1024);
            float4 wB1 = *reinterpret_cast<const float4*>(wbase + (ci + 1) * 1024 + 4);
            body(wA0, wB0, ci);
            int cn = (ci + 2 < 64) ? ci + 2 : 0;
            wA0 = *reinterpret_cast<const float4*>(wbase + cn * 1024);
            wB0 = *reinterpret_cast<const float4*>(wbase + cn * 1024 + 4);
            body(wA1, wB1, ci + 1);
        }
        float* yo = y1g + ((size_t)b * 128 + c) * 32 + t0;
#pragma unroll
        for (int u = 0; u < 15; ++u) yo[u] = elu1(acc[u]);
    }
}

// convB: conv2 + conv3 + state, GB batch elems per block. LDS 45KB -> 3 blocks/CU.
__global__ __launch_bounds__(256, 3)
void convB_kernel(const float* __restrict__ state_in,
                  const float* __restrict__ b2, const float* __restrict__ b3,
                  const float* __restrict__ W2T, const float* __restrict__ W3T,
                  const float* __restrict__ y1g,
                  float* __restrict__ out, float* __restrict__ r_ws) {
    __shared__ __align__(16) float y1s[GB * 128 * 32];
    __shared__ __align__(16) float y2s[GB * 256 * 6];

    const int tid = threadIdx.x;
    const int bbase = blockIdx.x * GB;

    // stage y1 (column-parallel: conflict-free LDS stores, coalesced global)
    {
        const int col = tid & 31, grp = tid >> 5;  // 8 groups of 16 rows
#pragma unroll
        for (int bi = 0; bi < GB; ++bi) {
            const float* src = y1g + ((size_t)(bbase + bi) * 128 + grp * 16) * 32 + col;
            float* dst = y1s + (bi * 128 + grp * 16) * 32 + col;
#pragma unroll
            for (int i = 0; i < 16; ++i) dst[i * 32] = src[i * 32];
        }
    }
    __syncthreads();
    // ---- conv2 (128->256, k=10, s=5) + ELU, ping-pong weight prefetch ----
    {
        const int c = tid;
        float acc[GB][6];
        float bias = b2[c];
#pragma unroll
        for (int bi = 0; bi < GB; ++bi)
#pragma unroll
            for (int t = 0; t < 6; ++t) acc[bi][t] = bias;
        const float* wbase = W2T + c * 10;  // + ci*2560

        auto loadw = [&](float* w, int ci) {
#pragma unroll
            for (int jj = 0; jj < 5; ++jj) {
                float2 wv = *reinterpret_cast<const float2*>(wbase + ci * 2560 + jj * 2);
                w[jj * 2] = wv.x; w[jj * 2 + 1] = wv.y;
            }
        };
        auto body = [&](const float* w, int ci) {
#pragma unroll
            for (int bi = 0; bi < GB; ++bi) {
                const float* yr = y1s + (bi * 128 + ci) * 32;
                float row[32];
#pragma unroll
                for (int k4 = 0; k4 < 8; ++k4) {
                    float4 v = *reinterpret_cast<const float4*>(yr + k4 * 4);
                    row[k4 * 4] = v.x; row[k4 * 4 + 1] = v.y;
                    row[k4 * 4 + 2] = v.z; row[k4 * 4 + 3] = v.w;
                }
                acc[bi][0] += w[5] * row[0] + w[6] * row[1] + w[7] * row[2]
                            + w[8] * row[3] + w[9] * row[4];
#pragma unroll
                for (int t = 1; t < 6; ++t) {
                    const int q0 = 5 * t - 5;
                    float s = 0.f;
#pragma unroll
                    for (int j = 0; j < 10; ++j) s += w[j] * row[q0 + j];
                    acc[bi][t] += s;
                }
            }
        };

        float wA_[10], wB_[10];
        loadw(wA_, 0);
        for (int ci = 0; ci < 128; ci += 2) {
            loadw(wB_, ci + 1);
            body(wA_, ci);
            loadw(wA_, (ci + 2 < 128) ? ci + 2 : 0);
            body(wB_, ci + 1);
        }
#pragma unroll
        for (int bi = 0; bi < GB; ++bi)
#pragma unroll
            for (int t = 0; t < 6; ++t)
                y2s[(bi * 256 + c) * 6 + t] = elu1(acc[bi][t]);
    }
    __syncthreads();
    // ---- conv3 (256->256): taps 6..11 only; no ELU ----
    {
        const int c = tid;
        float acc[GB];
        float bias = b3[c];
#pragma unroll
        for (int bi = 0; bi < GB; ++bi) acc[bi] = bias;
        const float* wbase = W3T + c * 6;  // + ci*1536

        auto body = [&](float2 w01, float2 w23, float2 w45, int ci) {
#pragma unroll
            for (int bi = 0; bi < GB; ++bi) {
                const float* yr = y2s + (bi * 256 + ci) * 6;
                float2 a = *reinterpret_cast<const float2*>(yr);
                float2 d = *reinterpret_cast<const float2*>(yr + 2);
                float2 e = *reinterpret_cast<const float2*>(yr + 4);
                acc[bi] += w01.x * a.x + w01.y * a.y + w23.x * d.x + w23.y * d.y
                         + w45.x * e.x + w45.y * e.y;
            }
        };

        float2 a0 = *reinterpret_cast<const float2*>(wbase);
        float2 a1 = *reinterpret_cast<const float2*>(wbase + 2);
        float2 a2 = *reinterpret_cast<const float2*>(wbase + 4);
        for (int ci = 0; ci < 256; ci += 2) {
            float2 c0 = *reinterpret_cast<const float2*>(wbase + (ci + 1) * 1536);
            float2 c1 = *reinterpret_cast<const float2*>(wbase + (ci + 1) * 1536 + 2);
            float2 c2 = *reinterpret_cast<const float2*>(wbase + (ci + 1) * 1536 + 4);
            body(a0, a1, a2, ci);
            int cn = (ci + 2 < 256) ? ci + 2 : 0;
            a0 = *reinterpret_cast<const float2*>(wbase + cn * 1536);
            a1 = *reinterpret_cast<const float2*>(wbase + cn * 1536 + 2);
            a2 = *reinterpret_cast<const float2*>(wbase + cn * 1536 + 4);
            body(c0, c1, c2, ci + 1);
        }
#pragma unroll
        for (int bi = 0; bi < GB; ++bi) {
            const int b = bbase + bi;
            float y3 = acc[bi];
            r_ws[b * 256 + c] = y3;
            float4 si = *reinterpret_cast<const float4*>(state_in + b * 1024 + c * 4);
            float4 o; o.x = si.y; o.y = si.z; o.z = si.w; o.w = y3;
            *reinterpret_cast<float4*>(out + 65536 + b * 1024 + c * 4) = o;
        }
    }
}

// ================= FALLBACK (round-2 fused, proven) =================
#define Y1S 36

__global__ __launch_bounds__(256, 2)
void conv_fused_kernel(const float* __restrict__ audio,
                       const float* __restrict__ state_in,
                       const float* __restrict__ W0, const float* __restrict__ b0,
                       const float* __restrict__ b1, const float* __restrict__ b2,
                       const float* __restrict__ b3,
                       const float* __restrict__ W1T, const float* __restrict__ W2T,
                       const float* __restrict__ W3T,
                       float* __restrict__ out, float* __restrict__ r_ws) {
    __shared__ __align__(16) float xs[244];
    __shared__ __align__(16) float y0s[64 * 124];
    __shared__ __align__(16) float y1s[GB * 128 * Y1S];
    __shared__ __align__(16) float y2s[GB * 256 * 6];

    const int tid = threadIdx.x;
    const int bbase = blockIdx.x * GB;

    if (tid < 64) {
        y0s[tid * 124 + 0] = 0.f; y0s[tid * 124 + 1] = 0.f;
        y0s[tid * 124 + 2] = 0.f; y0s[tid * 124 + 3] = 0.f;
    }

    for (int bi = 0; bi < GB; ++bi) {
        const int b = bbase + bi;
        __syncthreads();
        if (tid < 242) xs[tid] = (tid < 2) ? 0.f : audio[b * 240 + tid - 2];
        __syncthreads();
        {
            const int ci = tid >> 2, tg = tid & 3;
            float4 w = *reinterpret_cast<const float4*>(W0 + ci * 4);
            float bias = b0[ci];
            for (int t = tg; t < 120; t += 4) {
                float v = bias + w.x * xs[2 * t] + w.y * xs[2 * t + 1]
                               + w.z * xs[2 * t + 2] + w.w * xs[2 * t + 3];
                y0s[ci * 124 + 4 + t] = elu1(v);
            }
        }
        __syncthreads();
        {
            const int c = tid >> 1, half = tid & 1, t0 = 15 * half;
            float acc[15];
            float bias = b1[c];
#pragma unroll
            for (int u = 0; u < 15; ++u) acc[u] = bias;
            const float* wbase = W1T + c * 8;
            for (int ci = 0; ci < 64; ++ci) {
                float4 wA = *reinterpret_cast<const float4*>(wbase + ci * 1024);
                float4 wB = *reinterpret_cast<const float4*>(wbase + ci * 1024 + 4);
                const float* yb = y0s + ci * 124 + 4 * t0;
#pragma unroll
                for (int u = 0; u < 15; ++u) {
                    float4 a = *reinterpret_cast<const float4*>(yb + 4 * u);
                    float4 d = *reinterpret_cast<const float4*>(yb + 4 * u + 4);
                    acc[u] += wA.x * a.x + wA.y * a.y + wA.z * a.z + wA.w * a.w
                            + wB.x * d.x + wB.y * d.y + wB.z * d.z + wB.w * d.w;
                }
            }
            float* yo = y1s + (bi * 128 + c) * Y1S + t0;
#pragma unroll
            for (int u = 0; u < 15; ++u) yo[u] = elu1(acc[u]);
        }
    }
    __syncthreads();
    {
        const int c = tid;
        float acc[GB][6];
        float bias = b2[c];
#pragma unroll
        for (int bi = 0; bi < GB; ++bi)
#pragma unroll
            for (int t = 0; t < 6; ++t) acc[bi][t] = bias;
        const float* wbase = W2T + c * 10;
        for (int ci = 0; ci < 128; ++ci) {
            float w[10];
#pragma unroll
            for (int jj = 0; jj < 5; ++jj) {
                float2 wv = *reinterpret_cast<const float2*>(wbase + ci * 2560 + jj * 2);
                w[jj * 2] = wv.x; w[jj * 2 + 1] = wv.y;
            }
#pragma unroll
            for (int bi = 0; bi < GB; ++bi) {
                const float* yr = y1s + (bi * 128 + ci) * Y1S;
                float row[32];
#pragma unroll
                for (int k4 = 0; k4 < 8; ++k4) {
                    float4 v = *reinterpret_cast<const float4*>(yr + k4 * 4);
                    row[k4 * 4] = v.x; row[k4 * 4 + 1] = v.y;
                    row[k4 * 4 + 2] = v.z; row[k4 * 4 + 3] = v.w;
                }
                acc[bi][0] += w[5] * row[0] + w[6] * row[1] + w[7] * row[2]
                            + w[8] * row[3] + w[9] * row[4];
#pragma unroll
                for (int t = 1; t < 6; ++t) {
                    const int q0 = 5 * t - 5;
                    float s = 0.f;
#pragma unroll
                    for (int j = 0; j < 10; ++j) s += w[j] * row[q0 + j];
                    acc[bi][t] += s;
                }
            }
        }
#pragma unroll
        for (int bi = 0; bi < GB; ++bi)
#pragma unroll
            for (int t = 0; t < 6; ++t)
                y2s[(bi * 256 + c) * 6 + t] = elu1(acc[bi][t]);
    }
    __syncthreads();
    {
        const int c = tid;
        float acc[GB];
        float bias = b3[c];
#pragma unroll
        for (int bi = 0; bi < GB; ++bi) acc[bi] = bias;
        const float* wbase = W3T + c * 6;
        for (int ci = 0; ci < 256; ++ci) {
            float2 w01 = *reinterpret_cast<const float2*>(wbase + ci * 1536);
            float2 w23 = *reinterpret_cast<const float2*>(wbase + ci * 1536 + 2);
            float2 w45 = *reinterpret_cast<const float2*>(wbase + ci * 1536 + 4);
#pragma unroll
            for (int bi = 0; bi < GB; ++bi) {
                const float* yr = y2s + (bi * 256 + ci) * 6;
                float2 a = *reinterpret_cast<const float2*>(yr);
                float2 d = *reinterpret_cast<const float2*>(yr + 2);
                float2 e = *reinterpret_cast<const float2*>(yr + 4);
                acc[bi] += w01.x * a.x + w01.y * a.y + w23.x * d.x + w23.y * d.y
                         + w45.x * e.x + w45.y * e.y;
            }
        }
#pragma unroll
        for (int bi = 0; bi < GB; ++bi) {
            const int b = bbase + bi;
            float y3 = acc[bi];
            r_ws[b * 256 + c] = y3;
            float4 si = *reinterpret_cast<const float4*>(state_in + b * 1024 + c * 4);
            float4 o; o.x = si.y; o.y = si.z; o.z = si.w; o.w = y3;
            *reinterpret_cast<float4*>(out + 65536 + b * 1024 + c * 4) = o;
        }
    }
}

// ---------------- RVQ: 8 levels of argmin + residual update ----------------
__device__ __forceinline__ unsigned long long distkey(float d, int k) {
    unsigned u = __float_as_uint(d);
    u = (u & 0x80000000u) ? ~u : (u | 0x80000000u);  // monotonic float->uint
    return ((unsigned long long)u << 32) | (unsigned)k;  // low idx wins ties (np argmin)
}

__global__ __launch_bounds__(512)
void rvq_kernel(const float* __restrict__ cb, const float* __restrict__ cnorm,
                const float* __restrict__ r_ws, float* __restrict__ out) {
    __shared__ __align__(16) float rs[32 * 256];
    __shared__ __align__(16) float cbs[64 * 130];
    __shared__ int idx_sh[32];

    const int tid = threadIdx.x;
    const int b0 = blockIdx.x * 32;
    for (int it = 0; it < 4; ++it) {
        int o = (it * 512 + tid) * 4;
        *reinterpret_cast<float4*>(rs + o) =
            *reinterpret_cast<const float4*>(r_ws + b0 * 256 + o);
    }
    const int kk = tid & 63;
    const int bg = tid >> 6;
    const int dq = tid & 15;
    const int Kb = tid >> 4;

    for (int q = 0; q < 8; ++q) {
        unsigned long long keys[4];
#pragma unroll
        for (int i = 0; i < 4; ++i) keys[i] = 0xFFFFFFFFFFFFFFFFull;
        for (int kt = 0; kt < 8; ++kt) {
            const int k0 = kt * 128;
            float acc[2][4];
#pragma unroll
            for (int ci = 0; ci < 2; ++ci)
#pragma unroll
                for (int i = 0; i < 4; ++i) acc[ci][i] = 0.f;
            for (int dt = 0; dt < 4; ++dt) {
                __syncthreads();
#pragma unroll
                for (int p = 0; p < 4; ++p) {
                    int K = Kb + 32 * p;
                    float4 v = *reinterpret_cast<const float4*>(
                        cb + ((size_t)(q * 1024 + k0 + K)) * 256 + dt * 64 + 4 * dq);
                    cbs[(4 * dq + 0) * 130 + K] = v.x;
                    cbs[(4 * dq + 1) * 130 + K] = v.y;
                    cbs[(4 * dq + 2) * 130 + K] = v.z;
                    cbs[(4 * dq + 3) * 130 + K] = v.w;
                }
                __syncthreads();
                const int dbase = dt * 64;
#pragma unroll 4
                for (int d4 = 0; d4 < 16; ++d4) {
                    float rr[4][4];
#pragma unroll
                    for (int i = 0; i < 4; ++i) {
                        float4 rv = *reinterpret_cast<const float4*>(
                            rs + (bg * 4 + i) * 256 + dbase + d4 * 4);
                        rr[i][0] = rv.x; rr[i][1] = rv.y; rr[i][2] = rv.z; rr[i][3] = rv.w;
                    }
#pragma unroll
                    for (int e = 0; e < 4; ++e) {
                        float2 cv = *reinterpret_cast<const float2*>(
                            cbs + (d4 * 4 + e) * 130 + 2 * kk);
#pragma unroll
                        for (int i = 0; i < 4; ++i) {
                            acc[0][i] += cv.x * rr[i][e];
                            acc[1][i] += cv.y * rr[i][e];
                        }
                    }
                }
            }
            float2 cn = *reinterpret_cast<const float2*>(cnorm + q * 1024 + k0 + 2 * kk);
#pragma unroll
            for (int i = 0; i < 4; ++i) {
                float d0 = cn.x - 2.f * acc[0][i];
                float d1 = cn.y - 2.f * acc[1][i];
                unsigned long long ka = distkey(d0, k0 + 2 * kk);
                unsigned long long kb2 = distkey(d1, k0 + 2 * kk + 1);
                if (ka < keys[i]) keys[i] = ka;
                if (kb2 < keys[i]) keys[i] = kb2;
            }
        }
#pragma unroll
        for (int i = 0; i < 4; ++i) {
            unsigned long long k = keys[i];
            for (int off = 32; off >= 1; off >>= 1) {
                unsigned long long o = __shfl_xor(k, off, 64);
                if (o < k) k = o;
            }
            if (kk == 0) idx_sh[bg * 4 + i] = (int)(k & 0xFFFFFFFFu);
        }
        __syncthreads();
        for (int it = 0; it < 16; ++it) {
            int flat = it * 512 + tid;
            int bL = flat >> 8, d = flat & 255;
            rs[bL * 256 + d] -= cb[((size_t)(q * 1024 + idx_sh[bL])) * 256 + d];
        }
        if (tid < 32) out[(b0 + tid) * 8 + q] = (float)idx_sh[tid];
        __syncthreads();
    }
}

extern "C" void kernel_launch(void* const* d_in, const int* in_sizes, int n_in,
                              void* d_out, int out_size, void* d_ws, size_t ws_size,
                              hipStream_t stream) {
    const float* audio = (const float*)d_in[0];
    const float* state = (const float*)d_in[1];
    const float* W0 = (const float*)d_in[2];
    const float* b0 = (const float*)d_in[3];
    const float* W1 = (const float*)d_in[4];
    const float* b1 = (const float*)d_in[5];
    const float* W2 = (const float*)d_in[6];
    const float* b2 = (const float*)d_in[7];
    const float* W3 = (const float*)d_in[8];
    const float* b3 = (const float*)d_in[9];
    const float* cbk = (const float*)d_in[10];
    float* out = (float*)d_out;

    float* cnorm_ws = (float*)d_ws;            // 8192
    float* r_ws = cnorm_ws + 8192;             // 2097152
    float* W1T = r_ws + 2097152;               // 65536
    float* W2T = W1T + 65536;                  // 327680
    float* W3T = W2T + 327680;                 // 393216
    float* y1g = W3T + 393216;                 // 33554432 (134MB, split path only)

    const unsigned long long need = 36446208ull * 4ull;  // ~145.8 MB
    const bool split = ws_size >= need;

    cnorm_kernel<<<32, 256, 0, stream>>>(cbk, cnorm_ws);
    wtrans_kernel<<<416, 256, 0, stream>>>(W1, W2, W3, W1T, W2T, W3T);
    if (split) {
        convA_kernel<<<8192, 256, 0, stream>>>(audio, W0, b0, W1T, b1, y1g);
        convB_kernel<<<8192 / GB, 256, 0, stream>>>(state, b2, b3, W2T, W3T, y1g,
                                                    out, r_ws);
    } else {
        conv_fused_kernel<<<8192 / GB, 256, 0, stream>>>(audio, state, W0, b0, b1, b2,
                                                         b3, W1T, W2T, W3T, out, r_ws);
    }
    rvq_kernel<<<256, 512, 0, stream>>>(cbk, cnorm_ws, r_ws, out);
}

// Round 4
// 2361.339 us; speedup vs baseline: 3.0927x; 3.0927x over previous
//
#include <hip/hip_runtime.h>
#include <hip/hip_bf16.h>

#define GB 2  // batch elems per convB block

__device__ __forceinline__ float elu1(float v) { return v > 0.f ? v : expm1f(v); }

// ---------------- cnorm: ||cb_k||^2 per code ----------------
__global__ void cnorm_kernel(const float* __restrict__ cb, float* __restrict__ cnorm) {
    int g = blockIdx.x * blockDim.x + threadIdx.x;  // 0..8191  (q*1024+k)
    if (g >= 8 * 1024) return;
    const float* p = cb + (size_t)g * 256;
    float s = 0.f;
    for (int d = 0; d < 256; d += 4) {
        float4 v = *reinterpret_cast<const float4*>(p + d);
        s += v.x * v.x + v.y * v.y + v.z * v.z + v.w * v.w;
    }
    cnorm[g] = s;
}

// ---------------- weight transpose to lane-major layouts ----------------
__global__ void wtrans_kernel(const float* __restrict__ W1, const float* __restrict__ W2,
                              const float* __restrict__ W3, float* __restrict__ W1T,
                              float* __restrict__ W2T, float* __restrict__ W3T) {
    int g = blockIdx.x * blockDim.x + threadIdx.x;
    if (g < 8192) {  // W1
        int ci = g >> 7, c = g & 127;
        const float* src = W1 + c * 512 + ci * 8;
        float4 a = *reinterpret_cast<const float4*>(src);
        float4 b = *reinterpret_cast<const float4*>(src + 4);
        *reinterpret_cast<float4*>(W1T + g * 8) = a;
        *reinterpret_cast<float4*>(W1T + g * 8 + 4) = b;
    }
    int g2 = g - 8192;
    if (g2 >= 0 && g2 < 32768) {  // W2
        int ci = g2 >> 8, c = g2 & 255;
        const float* src = W2 + c * 1280 + ci * 10;
        float* dst = W2T + g2 * 10;
#pragma unroll
        for (int j = 0; j < 5; ++j)
            *reinterpret_cast<float2*>(dst + 2 * j) =
                *reinterpret_cast<const float2*>(src + 2 * j);
    }
    int g3 = g - 40960;
    if (g3 >= 0 && g3 < 65536) {  // W3 (only taps 6..11 are ever used)
        int ci = g3 >> 8, c = g3 & 255;
        const float* src = W3 + c * 3072 + ci * 12 + 6;
        float* dst = W3T + g3 * 6;
#pragma unroll
        for (int j = 0; j < 3; ++j)
            *reinterpret_cast<float2*>(dst + 2 * j) =
                *reinterpret_cast<const float2*>(src + 2 * j);
    }
}

// ================= convA: conv0 + conv1, one batch elem per block =================
// LDS ~33KB -> 4 blocks/CU. Round-2 verbatim bodies (no ping-pong, no lambdas,
// launch_bounds(256,2)) — the (256,4)+prefetch variant spilled 19GB to scratch.
__global__ __launch_bounds__(256, 2)
void convA_kernel(const float* __restrict__ audio,
                  const float* __restrict__ W0, const float* __restrict__ b0,
                  const float* __restrict__ W1T, const float* __restrict__ b1,
                  float* __restrict__ y1g) {
    __shared__ __align__(16) float xs[244];
    __shared__ __align__(16) float y0s[64 * 124];  // 4 left pad cols

    const int tid = threadIdx.x;
    const int b = blockIdx.x;

    if (tid < 64) {
        y0s[tid * 124 + 0] = 0.f; y0s[tid * 124 + 1] = 0.f;
        y0s[tid * 124 + 2] = 0.f; y0s[tid * 124 + 3] = 0.f;
    }
    if (tid < 242) xs[tid] = (tid < 2) ? 0.f : audio[b * 240 + tid - 2];
    __syncthreads();
    // ---- conv0 (1->64, k=4, s=2) + ELU ----
    {
        const int ci = tid >> 2, tg = tid & 3;
        float4 w = *reinterpret_cast<const float4*>(W0 + ci * 4);
        float bias = b0[ci];
        for (int t = tg; t < 120; t += 4) {
            float v = bias + w.x * xs[2 * t] + w.y * xs[2 * t + 1]
                           + w.z * xs[2 * t + 2] + w.w * xs[2 * t + 3];
            y0s[ci * 124 + 4 + t] = elu1(v);
        }
    }
    __syncthreads();
    // ---- conv1 (64->128, k=8, s=4) + ELU ----
    {
        const int c = tid >> 1, half = tid & 1, t0 = 15 * half;
        float acc[15];
        float bias = b1[c];
#pragma unroll
        for (int u = 0; u < 15; ++u) acc[u] = bias;
        const float* wbase = W1T + c * 8;  // + ci*1024
        for (int ci = 0; ci < 64; ++ci) {
            float4 wA = *reinterpret_cast<const float4*>(wbase + ci * 1024);
            float4 wB = *reinterpret_cast<const float4*>(wbase + ci * 1024 + 4);
            const float* yb = y0s + ci * 124 + 4 * t0;
#pragma unroll
            for (int u = 0; u < 15; ++u) {
                float4 a = *reinterpret_cast<const float4*>(yb + 4 * u);
                float4 d = *reinterpret_cast<const float4*>(yb + 4 * u + 4);
                acc[u] += wA.x * a.x + wA.y * a.y + wA.z * a.z + wA.w * a.w
                        + wB.x * d.x + wB.y * d.y + wB.z * d.z + wB.w * d.w;
            }
        }
        float* yo = y1g + ((size_t)b * 128 + c) * 32 + t0;
#pragma unroll
        for (int u = 0; u < 15; ++u) yo[u] = elu1(acc[u]);
    }
}

// ================= convB: conv2 + conv3 + state, GB batch elems per block ========
// LDS 45KB -> 3 blocks/CU. Round-2 verbatim conv2/conv3 bodies.
__global__ __launch_bounds__(256, 2)
void convB_kernel(const float* __restrict__ state_in,
                  const float* __restrict__ b2, const float* __restrict__ b3,
                  const float* __restrict__ W2T, const float* __restrict__ W3T,
                  const float* __restrict__ y1g,
                  float* __restrict__ out, float* __restrict__ r_ws) {
    __shared__ __align__(16) float y1s[GB * 128 * 32];
    __shared__ __align__(16) float y2s[GB * 256 * 6];

    const int tid = threadIdx.x;
    const int bbase = blockIdx.x * GB;

    // stage y1: col-parallel -> conflict-free LDS stores, coalesced global reads
    {
        const int col = tid & 31, grp = tid >> 5;  // 8 groups of 16 rows
#pragma unroll
        for (int bi = 0; bi < GB; ++bi) {
            const float* src = y1g + ((size_t)(bbase + bi) * 128 + grp * 16) * 32 + col;
            float* dst = y1s + (bi * 128 + grp * 16) * 32 + col;
#pragma unroll
            for (int i = 0; i < 16; ++i) dst[i * 32] = src[i * 32];
        }
    }
    __syncthreads();
    // ---- conv2 (128->256, k=10, s=5) + ELU ----
    {
        const int c = tid;
        float acc[GB][6];
        float bias = b2[c];
#pragma unroll
        for (int bi = 0; bi < GB; ++bi)
#pragma unroll
            for (int t = 0; t < 6; ++t) acc[bi][t] = bias;
        const float* wbase = W2T + c * 10;  // + ci*2560
        for (int ci = 0; ci < 128; ++ci) {
            float w[10];
#pragma unroll
            for (int jj = 0; jj < 5; ++jj) {
                float2 wv = *reinterpret_cast<const float2*>(wbase + ci * 2560 + jj * 2);
                w[jj * 2] = wv.x; w[jj * 2 + 1] = wv.y;
            }
#pragma unroll
            for (int bi = 0; bi < GB; ++bi) {
                const float* yr = y1s + (bi * 128 + ci) * 32;
                float row[32];
#pragma unroll
                for (int k4 = 0; k4 < 8; ++k4) {
                    float4 v = *reinterpret_cast<const float4*>(yr + k4 * 4);
                    row[k4 * 4] = v.x; row[k4 * 4 + 1] = v.y;
                    row[k4 * 4 + 2] = v.z; row[k4 * 4 + 3] = v.w;
                }
                acc[bi][0] += w[5] * row[0] + w[6] * row[1] + w[7] * row[2]
                            + w[8] * row[3] + w[9] * row[4];
#pragma unroll
                for (int t = 1; t < 6; ++t) {
                    const int q0 = 5 * t - 5;
                    float s = 0.f;
#pragma unroll
                    for (int j = 0; j < 10; ++j) s += w[j] * row[q0 + j];
                    acc[bi][t] += s;
                }
            }
        }
#pragma unroll
        for (int bi = 0; bi < GB; ++bi)
#pragma unroll
            for (int t = 0; t < 6; ++t)
                y2s[(bi * 256 + c) * 6 + t] = elu1(acc[bi][t]);
    }
    __syncthreads();
    // ---- conv3 (256->256): taps 6..11 only; no ELU ----
    {
        const int c = tid;
        float acc[GB];
        float bias = b3[c];
#pragma unroll
        for (int bi = 0; bi < GB; ++bi) acc[bi] = bias;
        const float* wbase = W3T + c * 6;  // + ci*1536
        for (int ci = 0; ci < 256; ++ci) {
            float2 w01 = *reinterpret_cast<const float2*>(wbase + ci * 1536);
            float2 w23 = *reinterpret_cast<const float2*>(wbase + ci * 1536 + 2);
            float2 w45 = *reinterpret_cast<const float2*>(wbase + ci * 1536 + 4);
#pragma unroll
            for (int bi = 0; bi < GB; ++bi) {
                const float* yr = y2s + (bi * 256 + ci) * 6;
                float2 a = *reinterpret_cast<const float2*>(yr);
                float2 d = *reinterpret_cast<const float2*>(yr + 2);
                float2 e = *reinterpret_cast<const float2*>(yr + 4);
                acc[bi] += w01.x * a.x + w01.y * a.y + w23.x * d.x + w23.y * d.y
                         + w45.x * e.x + w45.y * e.y;
            }
        }
#pragma unroll
        for (int bi = 0; bi < GB; ++bi) {
            const int b = bbase + bi;
            float y3 = acc[bi];
            r_ws[b * 256 + c] = y3;
            float4 si = *reinterpret_cast<const float4*>(state_in + b * 1024 + c * 4);
            float4 o; o.x = si.y; o.y = si.z; o.z = si.w; o.w = y3;
            *reinterpret_cast<float4*>(out + 65536 + b * 1024 + c * 4) = o;
        }
    }
}

// ---------------- RVQ: 8 levels of argmin + residual update ----------------
__device__ __forceinline__ unsigned long long distkey(float d, int k) {
    unsigned u = __float_as_uint(d);
    u = (u & 0x80000000u) ? ~u : (u | 0x80000000u);  // monotonic float->uint
    return ((unsigned long long)u << 32) | (unsigned)k;  // low idx wins ties (np argmin)
}

__global__ __launch_bounds__(512)
void rvq_kernel(const float* __restrict__ cb, const float* __restrict__ cnorm,
                const float* __restrict__ r_ws, float* __restrict__ out) {
    __shared__ __align__(16) float rs[32 * 256];
    __shared__ __align__(16) float cbs[64 * 130];
    __shared__ int idx_sh[32];

    const int tid = threadIdx.x;
    const int b0 = blockIdx.x * 32;
    for (int it = 0; it < 4; ++it) {
        int o = (it * 512 + tid) * 4;
        *reinterpret_cast<float4*>(rs + o) =
            *reinterpret_cast<const float4*>(r_ws + b0 * 256 + o);
    }
    const int kk = tid & 63;
    const int bg = tid >> 6;
    const int dq = tid & 15;
    const int Kb = tid >> 4;

    for (int q = 0; q < 8; ++q) {
        unsigned long long keys[4];
#pragma unroll
        for (int i = 0; i < 4; ++i) keys[i] = 0xFFFFFFFFFFFFFFFFull;
        for (int kt = 0; kt < 8; ++kt) {
            const int k0 = kt * 128;
            float acc[2][4];
#pragma unroll
            for (int ci = 0; ci < 2; ++ci)
#pragma unroll
                for (int i = 0; i < 4; ++i) acc[ci][i] = 0.f;
            for (int dt = 0; dt < 4; ++dt) {
                __syncthreads();
#pragma unroll
                for (int p = 0; p < 4; ++p) {
                    int K = Kb + 32 * p;
                    float4 v = *reinterpret_cast<const float4*>(
                        cb + ((size_t)(q * 1024 + k0 + K)) * 256 + dt * 64 + 4 * dq);
                    cbs[(4 * dq + 0) * 130 + K] = v.x;
                    cbs[(4 * dq + 1) * 130 + K] = v.y;
                    cbs[(4 * dq + 2) * 130 + K] = v.z;
                    cbs[(4 * dq + 3) * 130 + K] = v.w;
                }
                __syncthreads();
                const int dbase = dt * 64;
#pragma unroll 4
                for (int d4 = 0; d4 < 16; ++d4) {
                    float rr[4][4];
#pragma unroll
                    for (int i = 0; i < 4; ++i) {
                        float4 rv = *reinterpret_cast<const float4*>(
                            rs + (bg * 4 + i) * 256 + dbase + d4 * 4);
                        rr[i][0] = rv.x; rr[i][1] = rv.y; rr[i][2] = rv.z; rr[i][3] = rv.w;
                    }
#pragma unroll
                    for (int e = 0; e < 4; ++e) {
                        float2 cv = *reinterpret_cast<const float2*>(
                            cbs + (d4 * 4 + e) * 130 + 2 * kk);
#pragma unroll
                        for (int i = 0; i < 4; ++i) {
                            acc[0][i] += cv.x * rr[i][e];
                            acc[1][i] += cv.y * rr[i][e];
                        }
                    }
                }
            }
            float2 cn = *reinterpret_cast<const float2*>(cnorm + q * 1024 + k0 + 2 * kk);
#pragma unroll
            for (int i = 0; i < 4; ++i) {
                float d0 = cn.x - 2.f * acc[0][i];
                float d1 = cn.y - 2.f * acc[1][i];
                unsigned long long ka = distkey(d0, k0 + 2 * kk);
                unsigned long long kb2 = distkey(d1, k0 + 2 * kk + 1);
                if (ka < keys[i]) keys[i] = ka;
                if (kb2 < keys[i]) keys[i] = kb2;
            }
        }
#pragma unroll
        for (int i = 0; i < 4; ++i) {
            unsigned long long k = keys[i];
            for (int off = 32; off >= 1; off >>= 1) {
                unsigned long long o = __shfl_xor(k, off, 64);
                if (o < k) k = o;
            }
            if (kk == 0) idx_sh[bg * 4 + i] = (int)(k & 0xFFFFFFFFu);
        }
        __syncthreads();
        for (int it = 0; it < 16; ++it) {
            int flat = it * 512 + tid;
            int bL = flat >> 8, d = flat & 255;
            rs[bL * 256 + d] -= cb[((size_t)(q * 1024 + idx_sh[bL])) * 256 + d];
        }
        if (tid < 32) out[(b0 + tid) * 8 + q] = (float)idx_sh[tid];
        __syncthreads();
    }
}

extern "C" void kernel_launch(void* const* d_in, const int* in_sizes, int n_in,
                              void* d_out, int out_size, void* d_ws, size_t ws_size,
                              hipStream_t stream) {
    const float* audio = (const float*)d_in[0];
    const float* state = (const float*)d_in[1];
    const float* W0 = (const float*)d_in[2];
    const float* b0 = (const float*)d_in[3];
    const float* W1 = (const float*)d_in[4];
    const float* b1 = (const float*)d_in[5];
    const float* W2 = (const float*)d_in[6];
    const float* b2 = (const float*)d_in[7];
    const float* W3 = (const float*)d_in[8];
    const float* b3 = (const float*)d_in[9];
    const float* cbk = (const float*)d_in[10];
    float* out = (float*)d_out;

    float* cnorm_ws = (float*)d_ws;            // 8192
    float* r_ws = cnorm_ws + 8192;             // 2097152
    float* W1T = r_ws + 2097152;               // 65536
    float* W2T = W1T + 65536;                  // 327680
    float* W3T = W2T + 327680;                 // 393216
    float* y1g = W3T + 393216;                 // 33554432 (134MB; ws >=146MB confirmed r3)

    cnorm_kernel<<<32, 256, 0, stream>>>(cbk, cnorm_ws);
    wtrans_kernel<<<416, 256, 0, stream>>>(W1, W2, W3, W1T, W2T, W3T);
    convA_kernel<<<8192, 256, 0, stream>>>(audio, W0, b0, W1T, b1, y1g);
    convB_kernel<<<8192 / GB, 256, 0, stream>>>(state, b2, b3, W2T, W3T, y1g,
                                                out, r_ws);
    rvq_kernel<<<256, 512, 0, stream>>>(cbk, cnorm_ws, r_ws, out);
}

// Round 5
// 2072.547 us; speedup vs baseline: 3.5236x; 1.1393x over previous
//
#include <hip/hip_runtime.h>
#include <hip/hip_bf16.h>

#define GB 2  // batch elems per convB block

__device__ __forceinline__ float elu1(float v) { return v > 0.f ? v : expm1f(v); }

// ---------------- cnorm: ||cb_k||^2 per code ----------------
__global__ void cnorm_kernel(const float* __restrict__ cb, float* __restrict__ cnorm) {
    int g = blockIdx.x * blockDim.x + threadIdx.x;  // 0..8191  (q*1024+k)
    if (g >= 8 * 1024) return;
    const float* p = cb + (size_t)g * 256;
    float s = 0.f;
    for (int d = 0; d < 256; d += 4) {
        float4 v = *reinterpret_cast<const float4*>(p + d);
        s += v.x * v.x + v.y * v.y + v.z * v.z + v.w * v.w;
    }
    cnorm[g] = s;
}

// ---------------- weight transpose to lane-major layouts ----------------
__global__ void wtrans_kernel(const float* __restrict__ W1, const float* __restrict__ W2,
                              const float* __restrict__ W3, float* __restrict__ W1T,
                              float* __restrict__ W2T, float* __restrict__ W3T) {
    int g = blockIdx.x * blockDim.x + threadIdx.x;
    if (g < 8192) {  // W1
        int ci = g >> 7, c = g & 127;
        const float* src = W1 + c * 512 + ci * 8;
        float4 a = *reinterpret_cast<const float4*>(src);
        float4 b = *reinterpret_cast<const float4*>(src + 4);
        *reinterpret_cast<float4*>(W1T + g * 8) = a;
        *reinterpret_cast<float4*>(W1T + g * 8 + 4) = b;
    }
    int g2 = g - 8192;
    if (g2 >= 0 && g2 < 32768) {  // W2
        int ci = g2 >> 8, c = g2 & 255;
        const float* src = W2 + c * 1280 + ci * 10;
        float* dst = W2T + g2 * 10;
#pragma unroll
        for (int j = 0; j < 5; ++j)
            *reinterpret_cast<float2*>(dst + 2 * j) =
                *reinterpret_cast<const float2*>(src + 2 * j);
    }
    int g3 = g - 40960;
    if (g3 >= 0 && g3 < 65536) {  // W3 (only taps 6..11 are ever used)
        int ci = g3 >> 8, c = g3 & 255;
        const float* src = W3 + c * 3072 + ci * 12 + 6;
        float* dst = W3T + g3 * 6;
#pragma unroll
        for (int j = 0; j < 3; ++j)
            *reinterpret_cast<float2*>(dst + 2 * j) =
                *reinterpret_cast<const float2*>(src + 2 * j);
    }
}

// ================= convA: conv0 + conv1 (proven round-4 body) =================
__global__ __launch_bounds__(256, 2)
void convA_kernel(const float* __restrict__ audio,
                  const float* __restrict__ W0, const float* __restrict__ b0,
                  const float* __restrict__ W1T, const float* __restrict__ b1,
                  float* __restrict__ y1g) {
    __shared__ __align__(16) float xs[244];
    __shared__ __align__(16) float y0s[64 * 124];  // 4 left pad cols

    const int tid = threadIdx.x;
    const int b = blockIdx.x;

    if (tid < 64) {
        y0s[tid * 124 + 0] = 0.f; y0s[tid * 124 + 1] = 0.f;
        y0s[tid * 124 + 2] = 0.f; y0s[tid * 124 + 3] = 0.f;
    }
    if (tid < 242) xs[tid] = (tid < 2) ? 0.f : audio[b * 240 + tid - 2];
    __syncthreads();
    {
        const int ci = tid >> 2, tg = tid & 3;
        float4 w = *reinterpret_cast<const float4*>(W0 + ci * 4);
        float bias = b0[ci];
        for (int t = tg; t < 120; t += 4) {
            float v = bias + w.x * xs[2 * t] + w.y * xs[2 * t + 1]
                           + w.z * xs[2 * t + 2] + w.w * xs[2 * t + 3];
            y0s[ci * 124 + 4 + t] = elu1(v);
        }
    }
    __syncthreads();
    {
        const int c = tid >> 1, half = tid & 1, t0 = 15 * half;
        float acc[15];
        float bias = b1[c];
#pragma unroll
        for (int u = 0; u < 15; ++u) acc[u] = bias;
        const float* wbase = W1T + c * 8;  // + ci*1024
        for (int ci = 0; ci < 64; ++ci) {
            float4 wA = *reinterpret_cast<const float4*>(wbase + ci * 1024);
            float4 wB = *reinterpret_cast<const float4*>(wbase + ci * 1024 + 4);
            const float* yb = y0s + ci * 124 + 4 * t0;
#pragma unroll
            for (int u = 0; u < 15; ++u) {
                float4 a = *reinterpret_cast<const float4*>(yb + 4 * u);
                float4 d = *reinterpret_cast<const float4*>(yb + 4 * u + 4);
                acc[u] += wA.x * a.x + wA.y * a.y + wA.z * a.z + wA.w * a.w
                        + wB.x * d.x + wB.y * d.y + wB.z * d.z + wB.w * d.w;
            }
        }
        float* yo = y1g + ((size_t)b * 128 + c) * 32 + t0;
#pragma unroll
        for (int u = 0; u < 15; ++u) yo[u] = elu1(acc[u]);
    }
}

// ================= convB: conv2 + conv3 + state (proven round-4 body) ========
__global__ __launch_bounds__(256, 2)
void convB_kernel(const float* __restrict__ state_in,
                  const float* __restrict__ b2, const float* __restrict__ b3,
                  const float* __restrict__ W2T, const float* __restrict__ W3T,
                  const float* __restrict__ y1g,
                  float* __restrict__ out, float* __restrict__ r_ws) {
    __shared__ __align__(16) float y1s[GB * 128 * 32];
    __shared__ __align__(16) float y2s[GB * 256 * 6];

    const int tid = threadIdx.x;
    const int bbase = blockIdx.x * GB;

    {
        const int col = tid & 31, grp = tid >> 5;
#pragma unroll
        for (int bi = 0; bi < GB; ++bi) {
            const float* src = y1g + ((size_t)(bbase + bi) * 128 + grp * 16) * 32 + col;
            float* dst = y1s + (bi * 128 + grp * 16) * 32 + col;
#pragma unroll
            for (int i = 0; i < 16; ++i) dst[i * 32] = src[i * 32];
        }
    }
    __syncthreads();
    {
        const int c = tid;
        float acc[GB][6];
        float bias = b2[c];
#pragma unroll
        for (int bi = 0; bi < GB; ++bi)
#pragma unroll
            for (int t = 0; t < 6; ++t) acc[bi][t] = bias;
        const float* wbase = W2T + c * 10;
        for (int ci = 0; ci < 128; ++ci) {
            float w[10];
#pragma unroll
            for (int jj = 0; jj < 5; ++jj) {
                float2 wv = *reinterpret_cast<const float2*>(wbase + ci * 2560 + jj * 2);
                w[jj * 2] = wv.x; w[jj * 2 + 1] = wv.y;
            }
#pragma unroll
            for (int bi = 0; bi < GB; ++bi) {
                const float* yr = y1s + (bi * 128 + ci) * 32;
                float row[32];
#pragma unroll
                for (int k4 = 0; k4 < 8; ++k4) {
                    float4 v = *reinterpret_cast<const float4*>(yr + k4 * 4);
                    row[k4 * 4] = v.x; row[k4 * 4 + 1] = v.y;
                    row[k4 * 4 + 2] = v.z; row[k4 * 4 + 3] = v.w;
                }
                acc[bi][0] += w[5] * row[0] + w[6] * row[1] + w[7] * row[2]
                            + w[8] * row[3] + w[9] * row[4];
#pragma unroll
                for (int t = 1; t < 6; ++t) {
                    const int q0 = 5 * t - 5;
                    float s = 0.f;
#pragma unroll
                    for (int j = 0; j < 10; ++j) s += w[j] * row[q0 + j];
                    acc[bi][t] += s;
                }
            }
        }
#pragma unroll
        for (int bi = 0; bi < GB; ++bi)
#pragma unroll
            for (int t = 0; t < 6; ++t)
                y2s[(bi * 256 + c) * 6 + t] = elu1(acc[bi][t]);
    }
    __syncthreads();
    {
        const int c = tid;
        float acc[GB];
        float bias = b3[c];
#pragma unroll
        for (int bi = 0; bi < GB; ++bi) acc[bi] = bias;
        const float* wbase = W3T + c * 6;
        for (int ci = 0; ci < 256; ++ci) {
            float2 w01 = *reinterpret_cast<const float2*>(wbase + ci * 1536);
            float2 w23 = *reinterpret_cast<const float2*>(wbase + ci * 1536 + 2);
            float2 w45 = *reinterpret_cast<const float2*>(wbase + ci * 1536 + 4);
#pragma unroll
            for (int bi = 0; bi < GB; ++bi) {
                const float* yr = y2s + (bi * 256 + ci) * 6;
                float2 a = *reinterpret_cast<const float2*>(yr);
                float2 d = *reinterpret_cast<const float2*>(yr + 2);
                float2 e = *reinterpret_cast<const float2*>(yr + 4);
                acc[bi] += w01.x * a.x + w01.y * a.y + w23.x * d.x + w23.y * d.y
                         + w45.x * e.x + w45.y * e.y;
            }
        }
#pragma unroll
        for (int bi = 0; bi < GB; ++bi) {
            const int b = bbase + bi;
            float y3 = acc[bi];
            r_ws[b * 256 + c] = y3;
            float4 si = *reinterpret_cast<const float4*>(state_in + b * 1024 + c * 4);
            float4 o; o.x = si.y; o.y = si.z; o.z = si.w; o.w = y3;
            *reinterpret_cast<float4*>(out + 65536 + b * 1024 + c * 4) = o;
        }
    }
}

// ---------------- RVQ v2: register-tiled VALU-GEMM ----------------
// 512 thr = 8 waves: wave = (b-group of 8) x (k-half of 512); thread tile 8b x 8k.
// cbs: [16 d][1024 k] with column swizzle col=(k+4*d)&1023 -> conflict-free b128
// reads, 2-way (free) transpose stores. Stage prefetched 1 full stage ahead.
__device__ __forceinline__ unsigned long long distkey(float d, int k) {
    unsigned u = __float_as_uint(d);
    u = (u & 0x80000000u) ? ~u : (u | 0x80000000u);  // monotonic float->uint
    return ((unsigned long long)u << 32) | (unsigned)k;  // low idx wins ties (np argmin)
}

__global__ __launch_bounds__(512)
void rvq_kernel(const float* __restrict__ cb, const float* __restrict__ cnorm,
                const float* __restrict__ r_ws, float* __restrict__ out) {
    __shared__ __align__(16) float rs[32 * 256];    // 32 KB residuals
    __shared__ __align__(16) float cbs[16 * 1024];  // 64 KB, [d_local][k swizzled]
    __shared__ unsigned long long part_sh[2][32];
    __shared__ int idx_sh[32];

    const int tid = threadIdx.x;
    const int lane = tid & 63;
    const int wid = tid >> 6;   // 0..7
    const int bg = wid >> 1;    // 0..3: b block of 8
    const int kg = wid & 1;     // 0..1: k half of 512
    const int b0 = blockIdx.x * 32;
    const int kbase = kg * 512 + 4 * lane;

    // load residuals (coalesced, conflict-free)
    for (int it = 0; it < 4; ++it) {
        int o = (it * 512 + tid) * 4;
        *reinterpret_cast<float4*>(rs + o) =
            *reinterpret_cast<const float4*>(r_ws + b0 * 256 + o);
    }

    // staging roles: 4 threads per k-row cover 16 d
    const int sk = tid >> 2;   // 0..127
    const int sdq = tid & 3;   // d-quad

    // prefetch stage S=0 (q=0, ds=0)
    float v[8][4];
    {
        const float* src = cb + (size_t)sk * 256 + sdq * 4;
#pragma unroll
        for (int p = 0; p < 8; ++p) {
            float4 t = *reinterpret_cast<const float4*>(src + (size_t)p * 128 * 256);
            v[p][0] = t.x; v[p][1] = t.y; v[p][2] = t.z; v[p][3] = t.w;
        }
    }

    for (int q = 0; q < 8; ++q) {
        float acc[8][8];
#pragma unroll
        for (int i = 0; i < 8; ++i)
#pragma unroll
            for (int j = 0; j < 8; ++j) acc[i][j] = 0.f;

        for (int ds = 0; ds < 16; ++ds) {
            __syncthreads();  // all waves done reading cbs (previous stage)
            // transpose-store prefetched stage into cbs (2-way banked: free)
#pragma unroll
            for (int m = 0; m < 4; ++m) {
                const int d = sdq * 4 + m;
#pragma unroll
                for (int p = 0; p < 8; ++p) {
                    const int k = p * 128 + sk;
                    cbs[d * 1024 + ((k + 4 * d) & 1023)] = v[p][m];
                }
            }
            // prefetch next stage (clamped; harmless dup at the very end)
            {
                int Sn = q * 16 + ds + 1; if (Sn > 127) Sn = 127;
                const int qn = Sn >> 4, dsn = Sn & 15;
                const float* src = cb + ((size_t)(qn * 1024 + sk)) * 256 + dsn * 16 + sdq * 4;
#pragma unroll
                for (int p = 0; p < 8; ++p) {
                    float4 t = *reinterpret_cast<const float4*>(src + (size_t)p * 128 * 256);
                    v[p][0] = t.x; v[p][1] = t.y; v[p][2] = t.z; v[p][3] = t.w;
                }
            }
            __syncthreads();  // cbs stores visible
            // compute 16 d of this stage
#pragma unroll
            for (int c4 = 0; c4 < 4; ++c4) {
                float rr[8][4];
#pragma unroll
                for (int i = 0; i < 8; ++i) {
                    float4 t = *reinterpret_cast<const float4*>(
                        rs + (bg * 8 + i) * 256 + ds * 16 + c4 * 4);
                    rr[i][0] = t.x; rr[i][1] = t.y; rr[i][2] = t.z; rr[i][3] = t.w;
                }
#pragma unroll
                for (int dd = 0; dd < 4; ++dd) {
                    const int dl = c4 * 4 + dd;
                    float4 cv0 = *reinterpret_cast<const float4*>(
                        cbs + dl * 1024 + ((kbase + 4 * dl) & 1023));
                    float4 cv1 = *reinterpret_cast<const float4*>(
                        cbs + dl * 1024 + ((kbase + 256 + 4 * dl) & 1023));
#pragma unroll
                    for (int i = 0; i < 8; ++i) {
                        const float r = rr[i][dd];
                        acc[i][0] += r * cv0.x; acc[i][1] += r * cv0.y;
                        acc[i][2] += r * cv0.z; acc[i][3] += r * cv0.w;
                        acc[i][4] += r * cv1.x; acc[i][5] += r * cv1.y;
                        acc[i][6] += r * cv1.z; acc[i][7] += r * cv1.w;
                    }
                }
            }
        }
        // ---- argmin over this wave's 512-k half, 8 b's ----
        unsigned long long wkey[8];
#pragma unroll
        for (int i = 0; i < 8; ++i) wkey[i] = 0xFFFFFFFFFFFFFFFFull;
#pragma unroll
        for (int j = 0; j < 2; ++j) {
            float4 cn = *reinterpret_cast<const float4*>(
                cnorm + q * 1024 + kbase + 256 * j);
            float cne[4] = {cn.x, cn.y, cn.z, cn.w};
#pragma unroll
            for (int e = 0; e < 4; ++e) {
                const int kgl = kbase + 256 * j + e;
#pragma unroll
                for (int i = 0; i < 8; ++i) {
                    unsigned long long kk2 =
                        distkey(cne[e] - 2.f * acc[i][j * 4 + e], kgl);
                    if (kk2 < wkey[i]) wkey[i] = kk2;
                }
            }
        }
#pragma unroll
        for (int i = 0; i < 8; ++i) {
            unsigned long long k = wkey[i];
            for (int off = 32; off >= 1; off >>= 1) {
                unsigned long long o = __shfl_xor(k, off, 64);
                if (o < k) k = o;
            }
            if (lane == 0) part_sh[kg][bg * 8 + i] = k;
        }
        __syncthreads();
        if (tid < 32) {
            unsigned long long ka = part_sh[0][tid];
            unsigned long long kb = part_sh[1][tid];
            if (kb < ka) ka = kb;
            const int idx = (int)(ka & 0xFFFFFFFFu);
            idx_sh[tid] = idx;
            out[(b0 + tid) * 8 + q] = (float)idx;
        }
        __syncthreads();
        // residual update (coalesced global reads, conflict-free LDS rmw)
        for (int it = 0; it < 16; ++it) {
            int flat = it * 512 + tid;
            int bL = flat >> 8, d = flat & 255;
            rs[bL * 256 + d] -= cb[((size_t)(q * 1024 + idx_sh[bL])) * 256 + d];
        }
        // next q's first stage barrier makes these rs writes visible
    }
}

extern "C" void kernel_launch(void* const* d_in, const int* in_sizes, int n_in,
                              void* d_out, int out_size, void* d_ws, size_t ws_size,
                              hipStream_t stream) {
    const float* audio = (const float*)d_in[0];
    const float* state = (const float*)d_in[1];
    const float* W0 = (const float*)d_in[2];
    const float* b0 = (const float*)d_in[3];
    const float* W1 = (const float*)d_in[4];
    const float* b1 = (const float*)d_in[5];
    const float* W2 = (const float*)d_in[6];
    const float* b2 = (const float*)d_in[7];
    const float* W3 = (const float*)d_in[8];
    const float* b3 = (const float*)d_in[9];
    const float* cbk = (const float*)d_in[10];
    float* out = (float*)d_out;

    float* cnorm_ws = (float*)d_ws;            // 8192
    float* r_ws = cnorm_ws + 8192;             // 2097152
    float* W1T = r_ws + 2097152;               // 65536
    float* W2T = W1T + 65536;                  // 327680
    float* W3T = W2T + 327680;                 // 393216
    float* y1g = W3T + 393216;                 // 33554432 (134MB; ws >=146MB confirmed r3)

    cnorm_kernel<<<32, 256, 0, stream>>>(cbk, cnorm_ws);
    wtrans_kernel<<<416, 256, 0, stream>>>(W1, W2, W3, W1T, W2T, W3T);
    convA_kernel<<<8192, 256, 0, stream>>>(audio, W0, b0, W1T, b1, y1g);
    convB_kernel<<<8192 / GB, 256, 0, stream>>>(state, b2, b3, W2T, W3T, y1g,
                                                out, r_ws);
    rvq_kernel<<<256, 512, 0, stream>>>(cbk, cnorm_ws, r_ws, out);
}